// Round 2
// baseline (3000.000 us; speedup 1.0000x reference)
//
#include <hip/hip_runtime.h>
#include <hip/hip_bf16.h>

#define C_DIM 512
#define CQK_DIM 64
#define L_DIM 2048
#define B_DIM 8

// ---- workspace layout (fp32 elements) ----
static const size_t OFF_QT = 0;                        // [B][L][64]  = 1048576
static const size_t OFF_KT = OFF_QT + 1048576;         // [B][L][64]  = 1048576
static const size_t OFF_VT = OFF_KT + 1048576;         // [B][L][512] = 8388608
static const size_t OFF_O1 = OFF_VT + 8388608;         // [B][L][512] = 8388608
// total = 18,874,368 floats = 75.5 MB

// ---------------- K1: QKV projection ----------------
// grid: (L/256, 10, B). block 256. Each block: one batch, one 64-row tile of
// concat [Wq(64) | Wk(64) | Wv(512)], 256 l positions (one per thread).
// W accesses are wave-uniform -> scalar loads. x loads coalesced over l.
__global__ __launch_bounds__(256) void k_proj(const float* __restrict__ x,
                                              const float* __restrict__ Wq,
                                              const float* __restrict__ bq,
                                              const float* __restrict__ Wk,
                                              const float* __restrict__ bk,
                                              const float* __restrict__ Wv,
                                              const float* __restrict__ bv,
                                              float* __restrict__ qT,
                                              float* __restrict__ kT,
                                              float* __restrict__ vT) {
    const int b = blockIdx.z;
    const int ot = blockIdx.y;            // 0..9
    const int l = blockIdx.x * 256 + threadIdx.x;

    const float* W;
    const float* bias;
    if (ot == 0)      { W = Wq;                              bias = bq; }
    else if (ot == 1) { W = Wk;                              bias = bk; }
    else              { W = Wv + (size_t)(ot - 2) * 64 * 512; bias = bv + (ot - 2) * 64; }

    float acc[64];
#pragma unroll
    for (int oo = 0; oo < 64; ++oo) acc[oo] = bias[oo];

    const float* xp = x + (size_t)b * C_DIM * L_DIM + l;
    for (int c = 0; c < C_DIM; c += 4) {
        float xv0 = xp[(size_t)(c + 0) * L_DIM];
        float xv1 = xp[(size_t)(c + 1) * L_DIM];
        float xv2 = xp[(size_t)(c + 2) * L_DIM];
        float xv3 = xp[(size_t)(c + 3) * L_DIM];
#pragma unroll
        for (int oo = 0; oo < 64; ++oo) {
            const float* wr = W + oo * 512 + c;
            acc[oo] += wr[0] * xv0 + wr[1] * xv1 + wr[2] * xv2 + wr[3] * xv3;
        }
    }

    float* dst;
    if (ot == 0)      dst = qT + ((size_t)b * L_DIM + l) * 64;
    else if (ot == 1) dst = kT + ((size_t)b * L_DIM + l) * 64;
    else              dst = vT + ((size_t)b * L_DIM + l) * 512 + (ot - 2) * 64;
#pragma unroll
    for (int oo = 0; oo < 64; ++oo) dst[oo] = acc[oo];
}

// ---------------- K2: fused attention (2-phase softmax + PV) ----------------
// grid: (L/32, B). block 256. Each block: 32 query positions of one batch.
__global__ __launch_bounds__(256) void k_attn(const float* __restrict__ qT,
                                              const float* __restrict__ kT,
                                              const float* __restrict__ vT,
                                              float* __restrict__ out1) {
    const int b = blockIdx.y;
    const int q0 = blockIdx.x * 32;
    const int tid = threadIdx.x;
    const float scale = 0.125f;   // CQK^-0.5 = 1/8

    __shared__ float qs[32][68];      // +4 pad: spreads rows across banks
    __shared__ float ks[32][68];
    __shared__ float ps[32][33];
    __shared__ float red_m[32][8];
    __shared__ float red_s[32][8];
    __shared__ float m_sh[32];
    __shared__ float inv_s_sh[32];

    // stage q tile (32 rows x 64)
    {
        int r = tid >> 3, p = tid & 7;
        const float4* src = (const float4*)(qT + ((size_t)b * L_DIM + q0 + r) * 64 + p * 8);
        float4 a0 = src[0], a1 = src[1];
        *(float4*)&qs[r][p * 8]     = a0;
        *(float4*)&qs[r][p * 8 + 4] = a1;
    }
    __syncthreads();

    // ---- phase 1: exact row max & sumexp ----
    {
        int q1 = tid >> 3, sub = tid & 7;
        float m_loc = -1e30f, s_loc = 0.f;
        for (int j = 0; j < 256; ++j) {
            int k = sub + 8 * j;
            const float4* kr = (const float4*)(kT + ((size_t)b * L_DIM + k) * 64);
            float sc = 0.f;
#pragma unroll
            for (int c4 = 0; c4 < 16; ++c4) {
                float4 qv = *(const float4*)&qs[q1][c4 * 4];
                float4 kv = kr[c4];
                sc += qv.x * kv.x + qv.y * kv.y + qv.z * kv.z + qv.w * kv.w;
            }
            sc *= scale;
            float nm = fmaxf(m_loc, sc);
            s_loc = s_loc * __expf(m_loc - nm) + __expf(sc - nm);
            m_loc = nm;
        }
        red_m[q1][sub] = m_loc;
        red_s[q1][sub] = s_loc;
    }
    __syncthreads();
    if (tid < 32) {
        float M = -1e30f;
#pragma unroll
        for (int j = 0; j < 8; ++j) M = fmaxf(M, red_m[tid][j]);
        float S = 0.f;
#pragma unroll
        for (int j = 0; j < 8; ++j) S += red_s[tid][j] * __expf(red_m[tid][j] - M);
        m_sh[tid] = M;
        inv_s_sh[tid] = 1.f / S;
    }
    // (loop-top barrier below makes m_sh/inv_s_sh visible before first use)

    // ---- phase 2: PV with known normalization ----
    float4 acc[4][4];
#pragma unroll
    for (int i = 0; i < 4; ++i)
#pragma unroll
        for (int j = 0; j < 4; ++j) acc[i][j] = make_float4(0.f, 0.f, 0.f, 0.f);

    const int q2 = tid >> 3, k2b = tid & 7;     // score-compute mapping
    const int qg = tid >> 5, cg = tid & 31;     // PV mapping
    const int qb = qg * 4, cb = cg * 16;

    for (int t0 = 0; t0 < 64; ++t0) {
        const int k0 = t0 * 32;
        __syncthreads();   // protect ks/ps from previous tile's readers
        {
            int r = tid >> 3, p = tid & 7;
            const float4* src = (const float4*)(kT + ((size_t)b * L_DIM + k0 + r) * 64 + p * 8);
            float4 a0 = src[0], a1 = src[1];
            *(float4*)&ks[r][p * 8]     = a0;
            *(float4*)&ks[r][p * 8 + 4] = a1;
        }
        __syncthreads();
        {
            float sc[4] = {0.f, 0.f, 0.f, 0.f};
#pragma unroll
            for (int c4 = 0; c4 < 16; ++c4) {
                float4 qv = *(const float4*)&qs[q2][c4 * 4];
#pragma unroll
                for (int i = 0; i < 4; ++i) {
                    float4 kv = *(const float4*)&ks[k2b + 8 * i][c4 * 4];
                    sc[i] += qv.x * kv.x + qv.y * kv.y + qv.z * kv.z + qv.w * kv.w;
                }
            }
            float mm = m_sh[q2], iv = inv_s_sh[q2];
#pragma unroll
            for (int i = 0; i < 4; ++i)
                ps[q2][k2b + 8 * i] = __expf(sc[i] * scale - mm) * iv;
        }
        __syncthreads();
        {
            const float* vbase = vT + ((size_t)b * L_DIM + k0) * 512 + cb;
            for (int kk = 0; kk < 32; ++kk) {
                float pq[4];
#pragma unroll
                for (int i = 0; i < 4; ++i) pq[i] = ps[qb + i][kk];
                const float4* vp = (const float4*)(vbase + (size_t)kk * 512);
                float4 vv[4];
#pragma unroll
                for (int j = 0; j < 4; ++j) vv[j] = vp[j];
#pragma unroll
                for (int i = 0; i < 4; ++i) {
                    float p = pq[i];
#pragma unroll
                    for (int j = 0; j < 4; ++j) {
                        acc[i][j].x += p * vv[j].x;
                        acc[i][j].y += p * vv[j].y;
                        acc[i][j].z += p * vv[j].z;
                        acc[i][j].w += p * vv[j].w;
                    }
                }
            }
        }
    }

    // epilogue: out1[b][q][c]
#pragma unroll
    for (int i = 0; i < 4; ++i) {
        float4* dst = (float4*)(out1 + ((size_t)b * L_DIM + q0 + qb + i) * 512 + cb);
#pragma unroll
        for (int j = 0; j < 4; ++j) dst[j] = acc[i][j];
    }
}

// ---------------- K3: Wo GEMM + bias + residual ----------------
// grid: (L/256, 8, B). block 256. Same structure as K1.
__global__ __launch_bounds__(256) void k_out(const float* __restrict__ x,
                                             const float* __restrict__ Wo,
                                             const float* __restrict__ bo,
                                             const float* __restrict__ out1,
                                             float* __restrict__ out) {
    const int b = blockIdx.z;
    const int ot = blockIdx.y;            // 0..7
    const int l = blockIdx.x * 256 + threadIdx.x;
    const int o0 = ot * 64;

    const float* W = Wo + (size_t)o0 * 512;
    const float* bias = bo + o0;

    float acc[64];
#pragma unroll
    for (int oo = 0; oo < 64; ++oo) acc[oo] = bias[oo];

    const float* o1p = out1 + ((size_t)b * L_DIM + l) * 512;
    for (int c = 0; c < C_DIM; c += 4) {
        float4 xv = *(const float4*)(o1p + c);
#pragma unroll
        for (int oo = 0; oo < 64; ++oo) {
            const float* wr = W + oo * 512 + c;
            acc[oo] += wr[0] * xv.x + wr[1] * xv.y + wr[2] * xv.z + wr[3] * xv.w;
        }
    }

#pragma unroll
    for (int oo = 0; oo < 64; ++oo) {
        size_t xi = ((size_t)b * C_DIM + o0 + oo) * L_DIM + l;
        out[xi] = acc[oo] + x[xi];
    }
}

extern "C" void kernel_launch(void* const* d_in, const int* in_sizes, int n_in,
                              void* d_out, int out_size, void* d_ws, size_t ws_size,
                              hipStream_t stream) {
    const float* x  = (const float*)d_in[0];
    const float* Wq = (const float*)d_in[1];
    const float* bq = (const float*)d_in[2];
    const float* Wk = (const float*)d_in[3];
    const float* bk = (const float*)d_in[4];
    const float* Wv = (const float*)d_in[5];
    const float* bv = (const float*)d_in[6];
    const float* Wo = (const float*)d_in[7];
    const float* bo = (const float*)d_in[8];

    float* ws = (float*)d_ws;
    float* qT = ws + OFF_QT;
    float* kT = ws + OFF_KT;
    float* vT = ws + OFF_VT;
    float* o1 = ws + OFF_O1;
    float* out = (float*)d_out;

    k_proj<<<dim3(L_DIM / 256, 10, B_DIM), 256, 0, stream>>>(x, Wq, bq, Wk, bk, Wv, bv, qT, kT, vT);
    k_attn<<<dim3(L_DIM / 32, B_DIM), 256, 0, stream>>>(qT, kT, vT, o1);
    k_out<<<dim3(L_DIM / 256, 8, B_DIM), 256, 0, stream>>>(x, Wo, bo, o1, out);
}

// Round 3
// 1017.431 us; speedup vs baseline: 2.9486x; 2.9486x over previous
//
#include <hip/hip_runtime.h>
#include <hip/hip_bf16.h>

typedef __hip_bfloat16 bf16;
using bf16x8 = __attribute__((ext_vector_type(8))) short;
using f32x4  = __attribute__((ext_vector_type(4))) float;

#define C_DIM 512
#define CQK_DIM 64
#define L_DIM 2048
#define B_DIM 8

#define MFMA16(a, b, c) __builtin_amdgcn_mfma_f32_16x16x32_bf16(a, b, c, 0, 0, 0)

__device__ __forceinline__ short f2bf_s(float f) {
    bf16 h = __float2bfloat16(f);
    return *reinterpret_cast<short*>(&h);
}
__device__ __forceinline__ float bf2f(bf16 v) { return __bfloat162float(v); }

// ---- workspace layout (bytes) ----
// qT : [B][L][64]  bf16  (row-major: MFMA A/B fragment loads are contiguous)
// kT : [B][L][64]  bf16
// vTT: [B][C][L]   bf16  (channel-major: PV A-operand loads are contiguous)
// o1 : [B][C][L]   bf16  (attention output, channel-major)
static const size_t OFF_QT = 0;
static const size_t OFF_KT = OFF_QT + (size_t)B_DIM * L_DIM * 64 * 2;        // +4 MB
static const size_t OFF_VT = OFF_KT + (size_t)B_DIM * L_DIM * 64 * 2;        // +4 MB
static const size_t OFF_O1 = OFF_VT + (size_t)B_DIM * C_DIM * L_DIM * 2;     // +16 MB
// total 36 MB

// ---------------- K1: QKV projection (fp32 math, bf16 outputs) ----------------
// grid (L/256, 10, B), block 256. W loads wave-uniform (s_load); x coalesced over l.
__global__ __launch_bounds__(256) void k_proj(const float* __restrict__ x,
                                              const float* __restrict__ Wq,
                                              const float* __restrict__ bq,
                                              const float* __restrict__ Wk,
                                              const float* __restrict__ bk,
                                              const float* __restrict__ Wv,
                                              const float* __restrict__ bv,
                                              bf16* __restrict__ qT,
                                              bf16* __restrict__ kT,
                                              bf16* __restrict__ vTT) {
    const int b = blockIdx.z;
    const int ot = blockIdx.y;            // 0..9
    const int l = blockIdx.x * 256 + threadIdx.x;

    const float* W;
    const float* bias;
    if (ot == 0)      { W = Wq;                               bias = bq; }
    else if (ot == 1) { W = Wk;                               bias = bk; }
    else              { W = Wv + (size_t)(ot - 2) * 64 * 512;  bias = bv + (ot - 2) * 64; }

    float acc[64];
#pragma unroll
    for (int oo = 0; oo < 64; ++oo) acc[oo] = bias[oo];

    const float* xp = x + (size_t)b * C_DIM * L_DIM + l;
    for (int c = 0; c < C_DIM; c += 4) {
        float xv0 = xp[(size_t)(c + 0) * L_DIM];
        float xv1 = xp[(size_t)(c + 1) * L_DIM];
        float xv2 = xp[(size_t)(c + 2) * L_DIM];
        float xv3 = xp[(size_t)(c + 3) * L_DIM];
#pragma unroll
        for (int oo = 0; oo < 64; ++oo) {
            const float* wr = W + oo * 512 + c;
            acc[oo] += wr[0] * xv0 + wr[1] * xv1 + wr[2] * xv2 + wr[3] * xv3;
        }
    }

    if (ot == 0) {
        bf16* dst = qT + ((size_t)b * L_DIM + l) * 64;
#pragma unroll
        for (int oo = 0; oo < 64; ++oo) dst[oo] = __float2bfloat16(acc[oo]);
    } else if (ot == 1) {
        bf16* dst = kT + ((size_t)b * L_DIM + l) * 64;
#pragma unroll
        for (int oo = 0; oo < 64; ++oo) dst[oo] = __float2bfloat16(acc[oo]);
    } else {
        const int c0 = (ot - 2) * 64;
#pragma unroll
        for (int oo = 0; oo < 64; ++oo)
            vTT[((size_t)b * C_DIM + c0 + oo) * L_DIM + l] = __float2bfloat16(acc[oo]);
    }
}

// ---------------- K2: MFMA flash attention ----------------
// grid 512 blocks (batch-fast for XCD/L2 pinning), block 256 = 4 waves.
// Block: 32 queries x full C. Wave w: qh=w>>1 (q half), kh=w&1 (k half) for scores;
// c-range w*128..+127 for PV. O^T = V^T * P^T so V frags load contiguous from vTT.
__global__ __launch_bounds__(256) void k_attn(const bf16* __restrict__ qT,
                                              const bf16* __restrict__ kT,
                                              const bf16* __restrict__ vTT,
                                              bf16* __restrict__ o1) {
    const int bid = blockIdx.x;
    const int b = bid & 7;                 // batch -> XCD (heuristic, perf-only)
    const int q0 = (bid >> 3) * 32;
    const int tid = threadIdx.x;
    const int w = tid >> 6, lane = tid & 63;
    const int quad = lane >> 4, l15 = lane & 15;
    const int qh = w >> 1, kh = w & 1;
    const float scale = 0.125f;            // CQK^-0.5

    __shared__ short P_lds[32 * 40];       // pitch 40 shorts (80 B): 2-way conflicts only
    __shared__ float m_part[32][2], s_part[32][2];
    __shared__ float m_sh[32], is_sh[32];

    const size_t bL = (size_t)b * L_DIM;

    // Q fragments (A-layout: m=l15, ck=quad*8+j), reused in both phases
    const bf16* qrow = qT + (bL + q0 + qh * 16 + l15) * 64;
    bf16x8 qf0 = *(const bf16x8*)(qrow + quad * 8);
    bf16x8 qf1 = *(const bf16x8*)(qrow + 32 + quad * 8);

    // ---- phase 1: exact row max & sumexp via MFMA ----
    float m_loc[4], s_loc[4];
#pragma unroll
    for (int r = 0; r < 4; ++r) { m_loc[r] = -1e30f; s_loc[r] = 0.f; }

    for (int step = 0; step < 64; ++step) {
        const bf16* krow = kT + (bL + step * 32 + kh * 16 + l15) * 64;
        bf16x8 kf0 = *(const bf16x8*)(krow + quad * 8);
        bf16x8 kf1 = *(const bf16x8*)(krow + 32 + quad * 8);
        f32x4 s = {0.f, 0.f, 0.f, 0.f};
        s = MFMA16(qf0, kf0, s);
        s = MFMA16(qf1, kf1, s);
#pragma unroll
        for (int r = 0; r < 4; ++r) {
            float sc = s[r] * scale;
            float nm = fmaxf(m_loc[r], sc);
            s_loc[r] = s_loc[r] * __expf(m_loc[r] - nm) + __expf(sc - nm);
            m_loc[r] = nm;
        }
    }
    // butterfly over lane bits 0-3 (cols)
#pragma unroll
    for (int off = 1; off < 16; off <<= 1) {
#pragma unroll
        for (int r = 0; r < 4; ++r) {
            float mo = __shfl_xor(m_loc[r], off, 64);
            float so = __shfl_xor(s_loc[r], off, 64);
            float nm = fmaxf(m_loc[r], mo);
            s_loc[r] = s_loc[r] * __expf(m_loc[r] - nm) + so * __expf(mo - nm);
            m_loc[r] = nm;
        }
    }
    if (l15 == 0) {
#pragma unroll
        for (int r = 0; r < 4; ++r) {
            int row = qh * 16 + quad * 4 + r;
            m_part[row][kh] = m_loc[r];
            s_part[row][kh] = s_loc[r];
        }
    }
    __syncthreads();
    if (tid < 32) {
        float m0 = m_part[tid][0], m1 = m_part[tid][1];
        float M = fmaxf(m0, m1);
        float S = s_part[tid][0] * __expf(m0 - M) + s_part[tid][1] * __expf(m1 - M);
        m_sh[tid] = M;
        is_sh[tid] = 1.f / S;
    }
    __syncthreads();

    float mrow[4], ivrow[4];
#pragma unroll
    for (int r = 0; r < 4; ++r) {
        int row = qh * 16 + quad * 4 + r;
        mrow[r] = m_sh[row];
        ivrow[r] = is_sh[row];
    }

    // ---- phase 2: scores -> P (LDS) -> O^T += V^T * P^T ----
    f32x4 acc[2][8];
#pragma unroll
    for (int qg = 0; qg < 2; ++qg)
#pragma unroll
        for (int cg = 0; cg < 8; ++cg) acc[qg][cg] = (f32x4){0.f, 0.f, 0.f, 0.f};

    const bf16* vb = vTT + (size_t)b * C_DIM * L_DIM;

    for (int t = 0; t < 64; ++t) {
        const int k0 = t * 32;
        // wave's 16x16 score tile: rows qh*16.., cols k0+kh*16..
        const bf16* krow = kT + (bL + k0 + kh * 16 + l15) * 64;
        bf16x8 kf0 = *(const bf16x8*)(krow + quad * 8);
        bf16x8 kf1 = *(const bf16x8*)(krow + 32 + quad * 8);
        f32x4 s = {0.f, 0.f, 0.f, 0.f};
        s = MFMA16(qf0, kf0, s);
        s = MFMA16(qf1, kf1, s);
#pragma unroll
        for (int r = 0; r < 4; ++r) {
            float p = __expf(s[r] * scale - mrow[r]) * ivrow[r];
            P_lds[(qh * 16 + quad * 4 + r) * 40 + kh * 16 + l15] = f2bf_s(p);
        }
        __syncthreads();
        // P^T B-fragments: lane l15 = q col, reads P row l15 (and 16+l15), k=quad*8..
        bf16x8 pf0 = *(const bf16x8*)&P_lds[l15 * 40 + quad * 8];
        bf16x8 pf1 = *(const bf16x8*)&P_lds[(16 + l15) * 40 + quad * 8];
#pragma unroll
        for (int cg = 0; cg < 8; ++cg) {
            const bf16* vrow = vb + ((size_t)(w * 128 + cg * 16 + l15)) * L_DIM + k0 + quad * 8;
            bf16x8 vf = *(const bf16x8*)vrow;
            acc[0][cg] = MFMA16(vf, pf0, acc[0][cg]);
            acc[1][cg] = MFMA16(vf, pf1, acc[1][cg]);
        }
        __syncthreads();   // protect P_lds before next tile's writes
    }

    // epilogue: O^T C-layout -> o1[b][c][q] bf16
#pragma unroll
    for (int qg = 0; qg < 2; ++qg) {
#pragma unroll
        for (int cg = 0; cg < 8; ++cg) {
#pragma unroll
            for (int r = 0; r < 4; ++r) {
                int c = w * 128 + cg * 16 + quad * 4 + r;
                int qc = q0 + qg * 16 + l15;
                o1[((size_t)b * C_DIM + c) * L_DIM + qc] = __float2bfloat16(acc[qg][cg][r]);
            }
        }
    }
}

// ---------------- K3: Wo GEMM + bias + residual ----------------
// grid (L/256, 8, B), block 256. o1 reads now channel-major -> coalesced over l.
__global__ __launch_bounds__(256) void k_out(const float* __restrict__ x,
                                             const float* __restrict__ Wo,
                                             const float* __restrict__ bo,
                                             const bf16* __restrict__ o1,
                                             float* __restrict__ out) {
    const int b = blockIdx.z;
    const int ot = blockIdx.y;            // 0..7
    const int l = blockIdx.x * 256 + threadIdx.x;
    const int o0 = ot * 64;

    const float* W = Wo + (size_t)o0 * 512;
    const float* bias = bo + o0;

    float acc[64];
#pragma unroll
    for (int oo = 0; oo < 64; ++oo) acc[oo] = bias[oo];

    const bf16* o1p = o1 + (size_t)b * C_DIM * L_DIM + l;
    for (int c = 0; c < C_DIM; c += 4) {
        float xv0 = bf2f(o1p[(size_t)(c + 0) * L_DIM]);
        float xv1 = bf2f(o1p[(size_t)(c + 1) * L_DIM]);
        float xv2 = bf2f(o1p[(size_t)(c + 2) * L_DIM]);
        float xv3 = bf2f(o1p[(size_t)(c + 3) * L_DIM]);
#pragma unroll
        for (int oo = 0; oo < 64; ++oo) {
            const float* wr = W + oo * 512 + c;
            acc[oo] += wr[0] * xv0 + wr[1] * xv1 + wr[2] * xv2 + wr[3] * xv3;
        }
    }

#pragma unroll
    for (int oo = 0; oo < 64; ++oo) {
        size_t xi = ((size_t)b * C_DIM + o0 + oo) * L_DIM + l;
        out[xi] = acc[oo] + x[xi];
    }
}

extern "C" void kernel_launch(void* const* d_in, const int* in_sizes, int n_in,
                              void* d_out, int out_size, void* d_ws, size_t ws_size,
                              hipStream_t stream) {
    const float* x  = (const float*)d_in[0];
    const float* Wq = (const float*)d_in[1];
    const float* bq = (const float*)d_in[2];
    const float* Wk = (const float*)d_in[3];
    const float* bk = (const float*)d_in[4];
    const float* Wv = (const float*)d_in[5];
    const float* bv = (const float*)d_in[6];
    const float* Wo = (const float*)d_in[7];
    const float* bo = (const float*)d_in[8];

    char* wsb = (char*)d_ws;
    bf16* qT  = (bf16*)(wsb + OFF_QT);
    bf16* kT  = (bf16*)(wsb + OFF_KT);
    bf16* vTT = (bf16*)(wsb + OFF_VT);
    bf16* o1  = (bf16*)(wsb + OFF_O1);
    float* out = (float*)d_out;

    k_proj<<<dim3(L_DIM / 256, 10, B_DIM), 256, 0, stream>>>(x, Wq, bq, Wk, bk, Wv, bv, qT, kT, vTT);
    k_attn<<<dim3((L_DIM / 32) * B_DIM), 256, 0, stream>>>(qT, kT, vTT, o1);
    k_out<<<dim3(L_DIM / 256, 8, B_DIM), 256, 0, stream>>>(x, Wo, bo, o1, out);
}

// Round 4
// 373.403 us; speedup vs baseline: 8.0342x; 2.7248x over previous
//
#include <hip/hip_runtime.h>
#include <hip/hip_bf16.h>

typedef __hip_bfloat16 bf16;
using bf16x8 = __attribute__((ext_vector_type(8))) short;
using f32x4  = __attribute__((ext_vector_type(4))) float;

#define C_DIM 512
#define L_DIM 2048
#define B_DIM 8

#define MFMA16(a, b, c) __builtin_amdgcn_mfma_f32_16x16x32_bf16(a, b, c, 0, 0, 0)

__device__ __forceinline__ short f2bf_s(float f) {
    bf16 h = __float2bfloat16(f);
    return *reinterpret_cast<short*>(&h);
}

// ---- workspace layout (bytes) ----
// xT : [B][L][C] bf16   (k=c contiguous for projection fragments)
// Wxb: bf16 copies of weights (row-major [O][C], k=c contiguous)
// qT : [B][L][64] bf16, kT: [B][L][64] bf16
// vTT: [B][C][L] bf16   (k=l contiguous for PV B-fragments)
// o1 : [B][L][C] bf16   (k=c contiguous for k_out B-fragments)
static const size_t OFF_XT  = 0;                      // 16 MB
static const size_t OFF_WQB = 16777216;               // 64 KB
static const size_t OFF_WKB = 16842752;               // 64 KB
static const size_t OFF_WVB = 16908288;               // 512 KB
static const size_t OFF_WOB = 17432576;               // 512 KB
static const size_t OFF_QT  = 17956864;               // 2 MB
static const size_t OFF_KT  = 20054016;               // 2 MB
static const size_t OFF_VT  = 22151168;               // 16 MB
static const size_t OFF_O1  = 38928384;               // 16 MB
// total ~53.1 MB

// ---------------- K0a: weights fp32 -> bf16 ----------------
__global__ void k_wcvt(const float* __restrict__ Wq, const float* __restrict__ Wk,
                       const float* __restrict__ Wv, const float* __restrict__ Wo,
                       bf16* __restrict__ Wqb, bf16* __restrict__ Wkb,
                       bf16* __restrict__ Wvb, bf16* __restrict__ Wob) {
    int i = blockIdx.x * 256 + threadIdx.x;   // 0 .. 589823
    if (i < 32768)        Wqb[i]          = __float2bfloat16(Wq[i]);
    else if (i < 65536)   Wkb[i - 32768]  = __float2bfloat16(Wk[i - 32768]);
    else if (i < 327680)  Wvb[i - 65536]  = __float2bfloat16(Wv[i - 65536]);
    else                  Wob[i - 327680] = __float2bfloat16(Wo[i - 327680]);
}

// ---------------- K0b: transpose x [B][C][L] fp32 -> xT [B][L][C] bf16 ----------------
// grid (L/64, C/64, B), block 256. LDS 64x65 fp32 tile.
__global__ __launch_bounds__(256) void k_tr(const float* __restrict__ x,
                                            bf16* __restrict__ xT) {
    __shared__ float T[64][65];
    const int b = blockIdx.z;
    const int l0 = blockIdx.x * 64, c0 = blockIdx.y * 64;
    const int tx = threadIdx.x & 63, ty = threadIdx.x >> 6;   // ty 0..3

    const float* xp = x + ((size_t)b * C_DIM + c0) * L_DIM + l0;
#pragma unroll
    for (int i = 0; i < 16; ++i) {
        int c = i * 4 + ty;
        T[c][tx] = xp[(size_t)c * L_DIM + tx];
    }
    __syncthreads();
#pragma unroll
    for (int i = 0; i < 16; ++i) {
        int l = i * 4 + ty;
        xT[((size_t)b * L_DIM + l0 + l) * C_DIM + c0 + tx] = __float2bfloat16(T[tx][l]);
    }
}

// ---------------- K1: QKV projection via MFMA ----------------
// grid (16, 5, B), block 256 = 4 waves (2x2). y==0: q+k (wn=0->q, wn=1->k),
// y=1..4: v slice of 128 c_out rows. 64x64 tile per wave, K=512.
__global__ __launch_bounds__(256) void k_qkv(const bf16* __restrict__ xT,
                                             const bf16* __restrict__ Wqb, const float* __restrict__ bq,
                                             const bf16* __restrict__ Wkb, const float* __restrict__ bk,
                                             const bf16* __restrict__ Wvb, const float* __restrict__ bv,
                                             bf16* __restrict__ qT, bf16* __restrict__ kT,
                                             bf16* __restrict__ vTT) {
    const int b = blockIdx.z, y = blockIdx.y, bx = blockIdx.x;
    const int tid = threadIdx.x;
    const int w = tid >> 6, lane = tid & 63, quad = lane >> 4, l15 = lane & 15;
    const int wm = w >> 1, wn = w & 1;
    const size_t bL = (size_t)b * L_DIM;

    f32x4 acc[4][4];
#pragma unroll
    for (int i = 0; i < 4; ++i)
#pragma unroll
        for (int j = 0; j < 4; ++j) acc[i][j] = (f32x4){0.f, 0.f, 0.f, 0.f};

    if (y == 0) {
        // D[l][o] = sum_c xT[l][c] * W[o][c]
        const int mbase = bx * 128 + wm * 64;
        const bf16* Wb = wn ? Wkb : Wqb;
        const bf16* arow[4];
        const bf16* brow[4];
#pragma unroll
        for (int mi = 0; mi < 4; ++mi) arow[mi] = xT + (bL + mbase + mi * 16 + l15) * C_DIM;
#pragma unroll
        for (int ni = 0; ni < 4; ++ni) brow[ni] = Wb + (size_t)(ni * 16 + l15) * C_DIM;

        for (int kt = 0; kt < 16; ++kt) {
            const int ko = kt * 32 + quad * 8;
            bf16x8 af[4], bfr[4];
#pragma unroll
            for (int mi = 0; mi < 4; ++mi) af[mi] = *(const bf16x8*)(arow[mi] + ko);
#pragma unroll
            for (int ni = 0; ni < 4; ++ni) bfr[ni] = *(const bf16x8*)(brow[ni] + ko);
#pragma unroll
            for (int mi = 0; mi < 4; ++mi)
#pragma unroll
                for (int ni = 0; ni < 4; ++ni)
                    acc[mi][ni] = MFMA16(af[mi], bfr[ni], acc[mi][ni]);
        }

        const float* bias = wn ? bk : bq;
        bf16* dst = wn ? kT : qT;
        float bb[4];
#pragma unroll
        for (int ni = 0; ni < 4; ++ni) bb[ni] = bias[ni * 16 + l15];
#pragma unroll
        for (int mi = 0; mi < 4; ++mi)
#pragma unroll
            for (int r = 0; r < 4; ++r) {
                int l = mbase + mi * 16 + quad * 4 + r;
#pragma unroll
                for (int ni = 0; ni < 4; ++ni)
                    dst[(bL + l) * 64 + ni * 16 + l15] = __float2bfloat16(acc[mi][ni][r] + bb[ni]);
            }
    } else {
        // D[c_out][l] = sum_c Wv[c_out][c] * xT[l][c]
        const int cbase = (y - 1) * 128 + wm * 64;
        const int lbase = bx * 128 + wn * 64;
        const bf16* arow[4];
        const bf16* brow[4];
#pragma unroll
        for (int mi = 0; mi < 4; ++mi) arow[mi] = Wvb + (size_t)(cbase + mi * 16 + l15) * C_DIM;
#pragma unroll
        for (int ni = 0; ni < 4; ++ni) brow[ni] = xT + (bL + lbase + ni * 16 + l15) * C_DIM;

        for (int kt = 0; kt < 16; ++kt) {
            const int ko = kt * 32 + quad * 8;
            bf16x8 af[4], bfr[4];
#pragma unroll
            for (int mi = 0; mi < 4; ++mi) af[mi] = *(const bf16x8*)(arow[mi] + ko);
#pragma unroll
            for (int ni = 0; ni < 4; ++ni) bfr[ni] = *(const bf16x8*)(brow[ni] + ko);
#pragma unroll
            for (int mi = 0; mi < 4; ++mi)
#pragma unroll
                for (int ni = 0; ni < 4; ++ni)
                    acc[mi][ni] = MFMA16(af[mi], bfr[ni], acc[mi][ni]);
        }

#pragma unroll
        for (int mi = 0; mi < 4; ++mi)
#pragma unroll
            for (int r = 0; r < 4; ++r) {
                int c = cbase + mi * 16 + quad * 4 + r;
                float bb = bv[c];
#pragma unroll
                for (int ni = 0; ni < 4; ++ni)
                    vTT[((size_t)b * C_DIM + c) * L_DIM + lbase + ni * 16 + l15] =
                        __float2bfloat16(acc[mi][ni][r] + bb);
            }
    }
}

// ---------------- K2: MFMA flash attention ----------------
// grid 512 blocks (batch-fast), block 256 = 4 waves. Block: 32 q x full C.
// Phase 2: O = P*V (A=P from LDS, B=V from vTT), D[q][c] -> o1 [B][L][C].
__global__ __launch_bounds__(256) void k_attn(const bf16* __restrict__ qT,
                                              const bf16* __restrict__ kT,
                                              const bf16* __restrict__ vTT,
                                              bf16* __restrict__ o1) {
    const int bid = blockIdx.x;
    const int b = bid & 7;
    const int q0 = (bid >> 3) * 32;
    const int tid = threadIdx.x;
    const int w = tid >> 6, lane = tid & 63;
    const int quad = lane >> 4, l15 = lane & 15;
    const int qh = w >> 1, kh = w & 1;
    const float scale = 0.125f;

    __shared__ short P_lds[32 * 40];
    __shared__ float m_part[32][2], s_part[32][2];
    __shared__ float m_sh[32], is_sh[32];

    const size_t bL = (size_t)b * L_DIM;

    const bf16* qrow = qT + (bL + q0 + qh * 16 + l15) * 64;
    bf16x8 qf0 = *(const bf16x8*)(qrow + quad * 8);
    bf16x8 qf1 = *(const bf16x8*)(qrow + 32 + quad * 8);

    // ---- phase 1: exact row max & sumexp via MFMA ----
    float m_loc[4], s_loc[4];
#pragma unroll
    for (int r = 0; r < 4; ++r) { m_loc[r] = -1e30f; s_loc[r] = 0.f; }

    for (int step = 0; step < 64; ++step) {
        const bf16* krow = kT + (bL + step * 32 + kh * 16 + l15) * 64;
        bf16x8 kf0 = *(const bf16x8*)(krow + quad * 8);
        bf16x8 kf1 = *(const bf16x8*)(krow + 32 + quad * 8);
        f32x4 s = {0.f, 0.f, 0.f, 0.f};
        s = MFMA16(qf0, kf0, s);
        s = MFMA16(qf1, kf1, s);
#pragma unroll
        for (int r = 0; r < 4; ++r) {
            float sc = s[r] * scale;
            float nm = fmaxf(m_loc[r], sc);
            s_loc[r] = s_loc[r] * __expf(m_loc[r] - nm) + __expf(sc - nm);
            m_loc[r] = nm;
        }
    }
#pragma unroll
    for (int off = 1; off < 16; off <<= 1) {
#pragma unroll
        for (int r = 0; r < 4; ++r) {
            float mo = __shfl_xor(m_loc[r], off, 64);
            float so = __shfl_xor(s_loc[r], off, 64);
            float nm = fmaxf(m_loc[r], mo);
            s_loc[r] = s_loc[r] * __expf(m_loc[r] - nm) + so * __expf(mo - nm);
            m_loc[r] = nm;
        }
    }
    if (l15 == 0) {
#pragma unroll
        for (int r = 0; r < 4; ++r) {
            int row = qh * 16 + quad * 4 + r;
            m_part[row][kh] = m_loc[r];
            s_part[row][kh] = s_loc[r];
        }
    }
    __syncthreads();
    if (tid < 32) {
        float m0 = m_part[tid][0], m1 = m_part[tid][1];
        float M = fmaxf(m0, m1);
        float S = s_part[tid][0] * __expf(m0 - M) + s_part[tid][1] * __expf(m1 - M);
        m_sh[tid] = M;
        is_sh[tid] = 1.f / S;
    }
    __syncthreads();

    float mrow[4], ivrow[4];
#pragma unroll
    for (int r = 0; r < 4; ++r) {
        int row = qh * 16 + quad * 4 + r;
        mrow[r] = m_sh[row];
        ivrow[r] = is_sh[row];
    }

    // ---- phase 2: scores -> P (LDS) -> O += P * V ----
    f32x4 acc[2][8];
#pragma unroll
    for (int qg = 0; qg < 2; ++qg)
#pragma unroll
        for (int cg = 0; cg < 8; ++cg) acc[qg][cg] = (f32x4){0.f, 0.f, 0.f, 0.f};

    const bf16* vb = vTT + (size_t)b * C_DIM * L_DIM;

    for (int t = 0; t < 64; ++t) {
        const int k0 = t * 32;
        const bf16* krow = kT + (bL + k0 + kh * 16 + l15) * 64;
        bf16x8 kf0 = *(const bf16x8*)(krow + quad * 8);
        bf16x8 kf1 = *(const bf16x8*)(krow + 32 + quad * 8);
        f32x4 s = {0.f, 0.f, 0.f, 0.f};
        s = MFMA16(qf0, kf0, s);
        s = MFMA16(qf1, kf1, s);
#pragma unroll
        for (int r = 0; r < 4; ++r) {
            float p = __expf(s[r] * scale - mrow[r]) * ivrow[r];
            P_lds[(qh * 16 + quad * 4 + r) * 40 + kh * 16 + l15] = f2bf_s(p);
        }
        __syncthreads();
        // A-fragments of P: lane m=q=l15, k=quad*8+j
        bf16x8 pf0 = *(const bf16x8*)&P_lds[l15 * 40 + quad * 8];
        bf16x8 pf1 = *(const bf16x8*)&P_lds[(16 + l15) * 40 + quad * 8];
#pragma unroll
        for (int cg = 0; cg < 8; ++cg) {
            const bf16* vrow = vb + ((size_t)(w * 128 + cg * 16 + l15)) * L_DIM + k0 + quad * 8;
            bf16x8 vf = *(const bf16x8*)vrow;
            acc[0][cg] = MFMA16(pf0, vf, acc[0][cg]);
            acc[1][cg] = MFMA16(pf1, vf, acc[1][cg]);
        }
        __syncthreads();
    }

    // epilogue: D[q][c] C-layout -> o1[b][q][c]
#pragma unroll
    for (int qg = 0; qg < 2; ++qg) {
#pragma unroll
        for (int cg = 0; cg < 8; ++cg) {
#pragma unroll
            for (int r = 0; r < 4; ++r) {
                int q = q0 + qg * 16 + quad * 4 + r;
                int c = w * 128 + cg * 16 + l15;
                o1[(bL + q) * C_DIM + c] = __float2bfloat16(acc[qg][cg][r]);
            }
        }
    }
}

// ---------------- K3: Wo GEMM + bias + residual via MFMA ----------------
// grid (16, 4, B), block 256 = 4 waves (2x2). D[c_out][l], K=512.
__global__ __launch_bounds__(256) void k_out(const float* __restrict__ x,
                                             const bf16* __restrict__ Wob,
                                             const float* __restrict__ bo,
                                             const bf16* __restrict__ o1,
                                             float* __restrict__ out) {
    const int b = blockIdx.z;
    const int tid = threadIdx.x;
    const int w = tid >> 6, lane = tid & 63, quad = lane >> 4, l15 = lane & 15;
    const int wm = w >> 1, wn = w & 1;
    const int mbase = blockIdx.y * 128 + wm * 64;
    const int nbase = blockIdx.x * 128 + wn * 64;
    const size_t bL = (size_t)b * L_DIM;

    f32x4 acc[4][4];
#pragma unroll
    for (int i = 0; i < 4; ++i)
#pragma unroll
        for (int j = 0; j < 4; ++j) acc[i][j] = (f32x4){0.f, 0.f, 0.f, 0.f};

    const bf16* arow[4];
    const bf16* brow[4];
#pragma unroll
    for (int mi = 0; mi < 4; ++mi) arow[mi] = Wob + (size_t)(mbase + mi * 16 + l15) * C_DIM;
#pragma unroll
    for (int ni = 0; ni < 4; ++ni) brow[ni] = o1 + (bL + nbase + ni * 16 + l15) * C_DIM;

    for (int kt = 0; kt < 16; ++kt) {
        const int ko = kt * 32 + quad * 8;
        bf16x8 af[4], bfr[4];
#pragma unroll
        for (int mi = 0; mi < 4; ++mi) af[mi] = *(const bf16x8*)(arow[mi] + ko);
#pragma unroll
        for (int ni = 0; ni < 4; ++ni) bfr[ni] = *(const bf16x8*)(brow[ni] + ko);
#pragma unroll
        for (int mi = 0; mi < 4; ++mi)
#pragma unroll
            for (int ni = 0; ni < 4; ++ni)
                acc[mi][ni] = MFMA16(af[mi], bfr[ni], acc[mi][ni]);
    }

#pragma unroll
    for (int mi = 0; mi < 4; ++mi)
#pragma unroll
        for (int r = 0; r < 4; ++r) {
            int row = mbase + mi * 16 + quad * 4 + r;
            float bb = bo[row];
            size_t base = ((size_t)b * C_DIM + row) * L_DIM + nbase;
#pragma unroll
            for (int ni = 0; ni < 4; ++ni) {
                size_t idx = base + ni * 16 + l15;
                out[idx] = acc[mi][ni][r] + bb + x[idx];
            }
        }
}

extern "C" void kernel_launch(void* const* d_in, const int* in_sizes, int n_in,
                              void* d_out, int out_size, void* d_ws, size_t ws_size,
                              hipStream_t stream) {
    const float* x  = (const float*)d_in[0];
    const float* Wq = (const float*)d_in[1];
    const float* bq = (const float*)d_in[2];
    const float* Wk = (const float*)d_in[3];
    const float* bk = (const float*)d_in[4];
    const float* Wv = (const float*)d_in[5];
    const float* bv = (const float*)d_in[6];
    const float* Wo = (const float*)d_in[7];
    const float* bo = (const float*)d_in[8];

    char* wsb = (char*)d_ws;
    bf16* xT  = (bf16*)(wsb + OFF_XT);
    bf16* Wqb = (bf16*)(wsb + OFF_WQB);
    bf16* Wkb = (bf16*)(wsb + OFF_WKB);
    bf16* Wvb = (bf16*)(wsb + OFF_WVB);
    bf16* Wob = (bf16*)(wsb + OFF_WOB);
    bf16* qT  = (bf16*)(wsb + OFF_QT);
    bf16* kT  = (bf16*)(wsb + OFF_KT);
    bf16* vTT = (bf16*)(wsb + OFF_VT);
    bf16* o1  = (bf16*)(wsb + OFF_O1);
    float* out = (float*)d_out;

    k_wcvt<<<dim3(2304), 256, 0, stream>>>(Wq, Wk, Wv, Wo, Wqb, Wkb, Wvb, Wob);
    k_tr<<<dim3(L_DIM / 64, C_DIM / 64, B_DIM), 256, 0, stream>>>(x, xT);
    k_qkv<<<dim3(16, 5, B_DIM), 256, 0, stream>>>(xT, Wqb, bq, Wkb, bk, Wvb, bv, qT, kT, vTT);
    k_attn<<<dim3((L_DIM / 32) * B_DIM), 256, 0, stream>>>(qT, kT, vTT, o1);
    k_out<<<dim3(16, 4, B_DIM), 256, 0, stream>>>(x, Wob, bo, o1, out);
}

// Round 5
// 303.688 us; speedup vs baseline: 9.8786x; 1.2296x over previous
//
#include <hip/hip_runtime.h>
#include <hip/hip_bf16.h>

typedef __hip_bfloat16 bf16;
using bf16x8 = __attribute__((ext_vector_type(8))) short;
using f32x4  = __attribute__((ext_vector_type(4))) float;

#define C_DIM 512
#define L_DIM 2048
#define B_DIM 8

#define MFMA16(a, b, c) __builtin_amdgcn_mfma_f32_16x16x32_bf16(a, b, c, 0, 0, 0)

__device__ __forceinline__ short f2bf_s(float f) {
    bf16 h = __float2bfloat16(f);
    return *reinterpret_cast<short*>(&h);
}

// ---- workspace layout (bytes) ----
// xT : [B][L][C] bf16, Wxb: bf16 weights [O][C]
// qT/kT: [B][L][64] bf16, vTT: [B][C][L] bf16, o1: [B][L][C] bf16
static const size_t OFF_XT  = 0;                      // 16 MB
static const size_t OFF_WQB = 16777216;
static const size_t OFF_WKB = 16842752;
static const size_t OFF_WVB = 16908288;
static const size_t OFF_WOB = 17432576;
static const size_t OFF_QT  = 17956864;
static const size_t OFF_KT  = 20054016;
static const size_t OFF_VT  = 22151168;
static const size_t OFF_O1  = 38928384;

// ---------------- K0a: weights fp32 -> bf16 ----------------
__global__ void k_wcvt(const float* __restrict__ Wq, const float* __restrict__ Wk,
                       const float* __restrict__ Wv, const float* __restrict__ Wo,
                       bf16* __restrict__ Wqb, bf16* __restrict__ Wkb,
                       bf16* __restrict__ Wvb, bf16* __restrict__ Wob) {
    int i = blockIdx.x * 256 + threadIdx.x;
    if (i < 32768)        Wqb[i]          = __float2bfloat16(Wq[i]);
    else if (i < 65536)   Wkb[i - 32768]  = __float2bfloat16(Wk[i - 32768]);
    else if (i < 327680)  Wvb[i - 65536]  = __float2bfloat16(Wv[i - 65536]);
    else                  Wob[i - 327680] = __float2bfloat16(Wo[i - 327680]);
}

// ---------------- K0b: transpose x [B][C][L] fp32 -> xT [B][L][C] bf16 ----------------
__global__ __launch_bounds__(256) void k_tr(const float* __restrict__ x,
                                            bf16* __restrict__ xT) {
    __shared__ float T[64][65];
    const int b = blockIdx.z;
    const int l0 = blockIdx.x * 64, c0 = blockIdx.y * 64;
    const int tx = threadIdx.x & 63, ty = threadIdx.x >> 6;

    const float* xp = x + ((size_t)b * C_DIM + c0) * L_DIM + l0;
#pragma unroll
    for (int i = 0; i < 16; ++i) {
        int c = i * 4 + ty;
        T[c][tx] = xp[(size_t)c * L_DIM + tx];
    }
    __syncthreads();
#pragma unroll
    for (int i = 0; i < 16; ++i) {
        int l = i * 4 + ty;
        xT[((size_t)b * L_DIM + l0 + l) * C_DIM + c0 + tx] = __float2bfloat16(T[tx][l]);
    }
}

// ---------------- K1: QKV projection via MFMA (reg-prefetched K-loop) ----------------
__global__ __launch_bounds__(256, 2) void k_qkv(const bf16* __restrict__ xT,
                                                const bf16* __restrict__ Wqb, const float* __restrict__ bq,
                                                const bf16* __restrict__ Wkb, const float* __restrict__ bk,
                                                const bf16* __restrict__ Wvb, const float* __restrict__ bv,
                                                bf16* __restrict__ qT, bf16* __restrict__ kT,
                                                bf16* __restrict__ vTT) {
    const int b = blockIdx.z, y = blockIdx.y, bx = blockIdx.x;
    const int tid = threadIdx.x;
    const int w = tid >> 6, lane = tid & 63, quad = lane >> 4, l15 = lane & 15;
    const int wm = w >> 1, wn = w & 1;
    const size_t bL = (size_t)b * L_DIM;

    f32x4 acc[4][4];
#pragma unroll
    for (int i = 0; i < 4; ++i)
#pragma unroll
        for (int j = 0; j < 4; ++j) acc[i][j] = (f32x4){0.f, 0.f, 0.f, 0.f};

    const bf16* arow[4];
    const bf16* brow[4];
    if (y == 0) {
        const int mbase = bx * 128 + wm * 64;
        const bf16* Wb = wn ? Wkb : Wqb;
#pragma unroll
        for (int mi = 0; mi < 4; ++mi) arow[mi] = xT + (bL + mbase + mi * 16 + l15) * C_DIM;
#pragma unroll
        for (int ni = 0; ni < 4; ++ni) brow[ni] = Wb + (size_t)(ni * 16 + l15) * C_DIM;
    } else {
        const int cbase = (y - 1) * 128 + wm * 64;
        const int lbase = bx * 128 + wn * 64;
#pragma unroll
        for (int mi = 0; mi < 4; ++mi) arow[mi] = Wvb + (size_t)(cbase + mi * 16 + l15) * C_DIM;
#pragma unroll
        for (int ni = 0; ni < 4; ++ni) brow[ni] = xT + (bL + lbase + ni * 16 + l15) * C_DIM;
    }

    bf16x8 af[4], bfr[4], afn[4], bfn[4];
    {
        const int ko = quad * 8;
#pragma unroll
        for (int mi = 0; mi < 4; ++mi) af[mi] = *(const bf16x8*)(arow[mi] + ko);
#pragma unroll
        for (int ni = 0; ni < 4; ++ni) bfr[ni] = *(const bf16x8*)(brow[ni] + ko);
    }
    for (int kt = 0; kt < 16; ++kt) {
        if (kt < 15) {
            const int ko = (kt + 1) * 32 + quad * 8;
#pragma unroll
            for (int mi = 0; mi < 4; ++mi) afn[mi] = *(const bf16x8*)(arow[mi] + ko);
#pragma unroll
            for (int ni = 0; ni < 4; ++ni) bfn[ni] = *(const bf16x8*)(brow[ni] + ko);
        }
#pragma unroll
        for (int mi = 0; mi < 4; ++mi)
#pragma unroll
            for (int ni = 0; ni < 4; ++ni)
                acc[mi][ni] = MFMA16(af[mi], bfr[ni], acc[mi][ni]);
#pragma unroll
        for (int i = 0; i < 4; ++i) { af[i] = afn[i]; bfr[i] = bfn[i]; }
    }

    if (y == 0) {
        const int mbase = bx * 128 + wm * 64;
        const float* bias = wn ? bk : bq;
        bf16* dst = wn ? kT : qT;
        float bb[4];
#pragma unroll
        for (int ni = 0; ni < 4; ++ni) bb[ni] = bias[ni * 16 + l15];
#pragma unroll
        for (int mi = 0; mi < 4; ++mi)
#pragma unroll
            for (int r = 0; r < 4; ++r) {
                int l = mbase + mi * 16 + quad * 4 + r;
#pragma unroll
                for (int ni = 0; ni < 4; ++ni)
                    dst[(bL + l) * 64 + ni * 16 + l15] = __float2bfloat16(acc[mi][ni][r] + bb[ni]);
            }
    } else {
        const int cbase = (y - 1) * 128 + wm * 64;
        const int lbase = bx * 128 + wn * 64;
#pragma unroll
        for (int mi = 0; mi < 4; ++mi)
#pragma unroll
            for (int r = 0; r < 4; ++r) {
                int c = cbase + mi * 16 + quad * 4 + r;
                float bb = bv[c];
#pragma unroll
                for (int ni = 0; ni < 4; ++ni)
                    vTT[((size_t)b * C_DIM + c) * L_DIM + lbase + ni * 16 + l15] =
                        __float2bfloat16(acc[mi][ni][r] + bb);
            }
    }
}

// ---------------- K2: single-pass MFMA attention, unnormalized P + deferred 1/S ----------------
// grid 512 (b fast -> XCD pin), block 256 = 4 waves. Block: 64 q x 256 c (c-split 2).
// Wave w: score rows w*16..+15 (all k), PV c-slice w*64..+63.
// P~ = exp(min(s,60)-4) bf16 (shift-invariant; overflow-proof), S accumulated in regs,
// epilogue scales by 1/S. One barrier per k-tile (double-buffered P_lds).
__global__ __launch_bounds__(256, 2) void k_attn(const bf16* __restrict__ qT,
                                                 const bf16* __restrict__ kT,
                                                 const bf16* __restrict__ vTT,
                                                 bf16* __restrict__ o1) {
    const int bid = blockIdx.x;
    const int b = bid & 7;
    const int cs = (bid >> 3) & 1;
    const int q0 = (bid >> 4) * 64;
    const int c0 = cs * 256;
    const int tid = threadIdx.x;
    const int w = tid >> 6, lane = tid & 63;
    const int quad = lane >> 4, l15 = lane & 15;
    const float scale = 0.125f;

    __shared__ short P[2][64 * 40];     // pitch 40 shorts
    __shared__ float S_sh[64];

    const size_t bL = (size_t)b * L_DIM;

    // Q A-frags for wave's 16 rows
    const bf16* qrow = qT + (bL + q0 + w * 16 + l15) * 64;
    bf16x8 qf0 = *(const bf16x8*)(qrow + quad * 8);
    bf16x8 qf1 = *(const bf16x8*)(qrow + 32 + quad * 8);

    f32x4 acc[4][4];
#pragma unroll
    for (int i = 0; i < 4; ++i)
#pragma unroll
        for (int j = 0; j < 4; ++j) acc[i][j] = (f32x4){0.f, 0.f, 0.f, 0.f};
    float ssum[4] = {0.f, 0.f, 0.f, 0.f};

    // V row pointers (B-frag: n=c via l15, k=l via quad)
    const bf16* vrow[4];
#pragma unroll
    for (int cg = 0; cg < 4; ++cg)
        vrow[cg] = vTT + ((size_t)b * C_DIM + c0 + w * 64 + cg * 16 + l15) * L_DIM + quad * 8;

    const bf16* kb = kT + bL * 64;
    // K B-frags for tile 0: rows k0+kh*16+l15, ch halves h2
    bf16x8 kf[2][2], kfn[2][2];
#pragma unroll
    for (int kh = 0; kh < 2; ++kh)
#pragma unroll
        for (int h2 = 0; h2 < 2; ++h2)
            kf[kh][h2] = *(const bf16x8*)(kb + (size_t)(kh * 16 + l15) * 64 + h2 * 32 + quad * 8);

    for (int t = 0; t < 64; ++t) {
        const int k0 = t * 32;
        // issue this tile's V loads + next tile's K loads early (latency hidden
        // behind score MFMA + exp + barrier)
        bf16x8 vf[4];
#pragma unroll
        for (int cg = 0; cg < 4; ++cg) vf[cg] = *(const bf16x8*)(vrow[cg] + k0);
        if (t < 63) {
#pragma unroll
            for (int kh = 0; kh < 2; ++kh)
#pragma unroll
                for (int h2 = 0; h2 < 2; ++h2)
                    kfn[kh][h2] = *(const bf16x8*)(kb + (size_t)(k0 + 32 + kh * 16 + l15) * 64 + h2 * 32 + quad * 8);
        }

        short* Pb = P[t & 1];
#pragma unroll
        for (int kh = 0; kh < 2; ++kh) {
            f32x4 s = {0.f, 0.f, 0.f, 0.f};
            s = MFMA16(qf0, kf[kh][0], s);
            s = MFMA16(qf1, kf[kh][1], s);
#pragma unroll
            for (int r = 0; r < 4; ++r) {
                float p = __expf(fminf(s[r] * scale, 60.f) - 4.f);
                short pb = f2bf_s(p);
                bf16 pbh = *reinterpret_cast<bf16*>(&pb);
                ssum[r] += __bfloat162float(pbh);     // S from the rounded values
                Pb[(w * 16 + quad * 4 + r) * 40 + kh * 16 + l15] = pb;
            }
        }
        __syncthreads();
        bf16x8 pf[4];
#pragma unroll
        for (int qg = 0; qg < 4; ++qg)
            pf[qg] = *(const bf16x8*)&Pb[(qg * 16 + l15) * 40 + quad * 8];
#pragma unroll
        for (int qg = 0; qg < 4; ++qg)
#pragma unroll
            for (int cg = 0; cg < 4; ++cg)
                acc[qg][cg] = MFMA16(pf[qg], vf[cg], acc[qg][cg]);
#pragma unroll
        for (int kh = 0; kh < 2; ++kh)
#pragma unroll
            for (int h2 = 0; h2 < 2; ++h2) kf[kh][h2] = kfn[kh][h2];
    }

    // reduce S over the 16 score columns (lane bits 0-3)
#pragma unroll
    for (int off = 1; off < 16; off <<= 1)
#pragma unroll
        for (int r = 0; r < 4; ++r) ssum[r] += __shfl_xor(ssum[r], off, 64);
    if (l15 == 0) {
#pragma unroll
        for (int r = 0; r < 4; ++r) S_sh[w * 16 + quad * 4 + r] = ssum[r];
    }
    __syncthreads();
    if (tid < 64) S_sh[tid] = 1.f / S_sh[tid];
    __syncthreads();

    // epilogue: normalize + write o1[b][q][c]
#pragma unroll
    for (int qg = 0; qg < 4; ++qg) {
        float inv[4];
#pragma unroll
        for (int r = 0; r < 4; ++r) inv[r] = S_sh[qg * 16 + quad * 4 + r];
#pragma unroll
        for (int r = 0; r < 4; ++r) {
            const size_t base = (bL + q0 + qg * 16 + quad * 4 + r) * C_DIM + c0 + w * 64;
#pragma unroll
            for (int cg = 0; cg < 4; ++cg)
                o1[base + cg * 16 + l15] = __float2bfloat16(acc[qg][cg][r] * inv[r]);
        }
    }
}

// ---------------- K3: Wo GEMM + bias + residual via MFMA (reg-prefetched) ----------------
__global__ __launch_bounds__(256, 2) void k_out(const float* __restrict__ x,
                                                const bf16* __restrict__ Wob,
                                                const float* __restrict__ bo,
                                                const bf16* __restrict__ o1,
                                                float* __restrict__ out) {
    const int b = blockIdx.z;
    const int tid = threadIdx.x;
    const int w = tid >> 6, lane = tid & 63, quad = lane >> 4, l15 = lane & 15;
    const int wm = w >> 1, wn = w & 1;
    const int mbase = blockIdx.y * 128 + wm * 64;
    const int nbase = blockIdx.x * 128 + wn * 64;
    const size_t bL = (size_t)b * L_DIM;

    f32x4 acc[4][4];
#pragma unroll
    for (int i = 0; i < 4; ++i)
#pragma unroll
        for (int j = 0; j < 4; ++j) acc[i][j] = (f32x4){0.f, 0.f, 0.f, 0.f};

    const bf16* arow[4];
    const bf16* brow[4];
#pragma unroll
    for (int mi = 0; mi < 4; ++mi) arow[mi] = Wob + (size_t)(mbase + mi * 16 + l15) * C_DIM;
#pragma unroll
    for (int ni = 0; ni < 4; ++ni) brow[ni] = o1 + (bL + nbase + ni * 16 + l15) * C_DIM;

    bf16x8 af[4], bfr[4], afn[4], bfn[4];
    {
        const int ko = quad * 8;
#pragma unroll
        for (int mi = 0; mi < 4; ++mi) af[mi] = *(const bf16x8*)(arow[mi] + ko);
#pragma unroll
        for (int ni = 0; ni < 4; ++ni) bfr[ni] = *(const bf16x8*)(brow[ni] + ko);
    }
    for (int kt = 0; kt < 16; ++kt) {
        if (kt < 15) {
            const int ko = (kt + 1) * 32 + quad * 8;
#pragma unroll
            for (int mi = 0; mi < 4; ++mi) afn[mi] = *(const bf16x8*)(arow[mi] + ko);
#pragma unroll
            for (int ni = 0; ni < 4; ++ni) bfn[ni] = *(const bf16x8*)(brow[ni] + ko);
        }
#pragma unroll
        for (int mi = 0; mi < 4; ++mi)
#pragma unroll
            for (int ni = 0; ni < 4; ++ni)
                acc[mi][ni] = MFMA16(af[mi], bfr[ni], acc[mi][ni]);
#pragma unroll
        for (int i = 0; i < 4; ++i) { af[i] = afn[i]; bfr[i] = bfn[i]; }
    }

#pragma unroll
    for (int mi = 0; mi < 4; ++mi)
#pragma unroll
        for (int r = 0; r < 4; ++r) {
            int row = mbase + mi * 16 + quad * 4 + r;
            float bb = bo[row];
            size_t base = ((size_t)b * C_DIM + row) * L_DIM + nbase;
#pragma unroll
            for (int ni = 0; ni < 4; ++ni) {
                size_t idx = base + ni * 16 + l15;
                out[idx] = acc[mi][ni][r] + bb + x[idx];
            }
        }
}

extern "C" void kernel_launch(void* const* d_in, const int* in_sizes, int n_in,
                              void* d_out, int out_size, void* d_ws, size_t ws_size,
                              hipStream_t stream) {
    const float* x  = (const float*)d_in[0];
    const float* Wq = (const float*)d_in[1];
    const float* bq = (const float*)d_in[2];
    const float* Wk = (const float*)d_in[3];
    const float* bk = (const float*)d_in[4];
    const float* Wv = (const float*)d_in[5];
    const float* bv = (const float*)d_in[6];
    const float* Wo = (const float*)d_in[7];
    const float* bo = (const float*)d_in[8];

    char* wsb = (char*)d_ws;
    bf16* xT  = (bf16*)(wsb + OFF_XT);
    bf16* Wqb = (bf16*)(wsb + OFF_WQB);
    bf16* Wkb = (bf16*)(wsb + OFF_WKB);
    bf16* Wvb = (bf16*)(wsb + OFF_WVB);
    bf16* Wob = (bf16*)(wsb + OFF_WOB);
    bf16* qT  = (bf16*)(wsb + OFF_QT);
    bf16* kT  = (bf16*)(wsb + OFF_KT);
    bf16* vTT = (bf16*)(wsb + OFF_VT);
    bf16* o1  = (bf16*)(wsb + OFF_O1);
    float* out = (float*)d_out;

    k_wcvt<<<dim3(2304), 256, 0, stream>>>(Wq, Wk, Wv, Wo, Wqb, Wkb, Wvb, Wob);
    k_tr<<<dim3(L_DIM / 64, C_DIM / 64, B_DIM), 256, 0, stream>>>(x, xT);
    k_qkv<<<dim3(16, 5, B_DIM), 256, 0, stream>>>(xT, Wqb, bq, Wkb, bk, Wvb, bv, qT, kT, vTT);
    k_attn<<<dim3(512), 256, 0, stream>>>(qT, kT, vTT, o1);
    k_out<<<dim3(16, 4, B_DIM), 256, 0, stream>>>(x, Wob, bo, o1, out);
}